// Round 14
// baseline (92.967 us; speedup 1.0000x reference)
//
#include <hip/hip_runtime.h>

// SLAYER SRM-alpha constants (fp32-rounded from the reference doubles)
#define D_SR   0.90483741803595952f   // exp(-1/10)
#define D_REF  0.36787944117144233f   // exp(-1)
#define PSPSC  0.27182818284590454f   // e/10
#define THETA  10.0f
#define REFSC  20.0f                  // scaleRef * theta
#define POOLSC 2.75f                  // 1.1*theta/4
// Safe upper bound on the psp gain sum (e/10)*sum_{s} s*d^s = 27.160...
#define PSPBND 27.2f
// f16-conv absolute error bound (25-term pk_fma accumulation + RTZ pack of
// binary inputs, |v|<~1): worst-case ~4e-3; use 6e-3 for margin.
#define F16EPS 0.006f

typedef __fp16 h2 __attribute__((ext_vector_type(2)));  // matches cvt_pkrtz

// One SRM step: two cascaded IIR stages (alpha PSP), threshold, exp refractory.
__device__ __forceinline__ float snstep(float x, float& g1, float& g2, float& r) {
  g1 = D_SR * g1 + x;
  g2 = D_SR * g2 + g1;
  const float u = PSPSC * (g2 - g1) + r - THETA;
  const float s = (u >= 0.0f) ? 1.0f : 0.0f;
  r = D_REF * (r - REFSC * s);
  return s;
}

__device__ __forceinline__ int snstep_i(float x, float& g1, float& g2, float& r) {
  g1 = D_SR * g1 + x;
  g2 = D_SR * g2 + g1;
  const float u = PSPSC * (g2 - g1) + r - THETA;
  const int s = (u >= 0.0f) ? 1 : 0;
  r = D_REF * (r - REFSC * (float)s);
  return s;
}

// jax.image.resize bilinear 2x coeffs (clamped): validated absmax=0 R0-R12.
__device__ __forceinline__ void upcoef(int o, int I, int& i0, int& i1,
                                       float& f0, float& f1) {
  const int k = o >> 1;
  if (o & 1) { i0 = k; i1 = (k + 1 < I) ? k + 1 : I - 1; f0 = 0.75f; f1 = 0.25f; }
  else       { i0 = (k > 0) ? k - 1 : 0; i1 = k;         f0 = 0.25f; f1 = 0.75f; }
}

// ---------------------------------------------------------------------------
// L1 fused: conv5x5 (Ci=1) + psp + spike-existence + d_out zero.
// Common-path conv in PACKED F16 (v_pk_fma_f16, 2 FMA/instr — input is
// binary so x is exact in f16; |w| rounding <= 3e-5) with an F16EPS-guarded
// existence bound. Triggered waves (~1.3%) recompute the conv in EXACT fp32
// and run the unchanged per-channel bound -> Kogge-Stone scan -> existence ->
// dump path, so final spike decisions are identical to the validated R12 path.
// Channel-split: block handles 8 of 16 channels (cg = blockIdx&1).
// Existence: r<=0 invariant => spike iff max_t a_t >= theta;
// |a_t| <= PSPBND*max|v|.
// NOTE (R9 lesson): every loop touching acc arrays MUST be fully unrolled —
// rolled loops dynamically index them and demote to scratch.
// Flags use ==1u semantics (0xAA ws-poison reads as unset -> no init).
// ---------------------------------------------------------------------------
#define SCANSTEP(DELTA, CK, MK)                                         \
  { float o1 = __shfl_up(s1v, DELTA, 64);                               \
    float o2 = __shfl_up(s2v, DELTA, 64);                               \
    if (lane < DELTA) { o1 = 0.f; o2 = 0.f; }                           \
    s2v = fmaf(CK, fmaf(MK, o1, o2), s2v);                              \
    s1v = fmaf(CK, o1, s1v); }

__global__ __launch_bounds__(256)
void l1_fused(const float* __restrict__ in, const float* __restrict__ wt,
              float* __restrict__ Vr, unsigned char* __restrict__ dpix,
              unsigned* __restrict__ dirty, float* __restrict__ dout) {
  const int H = 32, W = 32, K = 5, P = 2;
  __shared__ float wlds[25 * 8];          // fp32 weights (rare exact path)
  __shared__ h2    whds[25 * 8];          // (w,w) packed f16 (common path)
  const int tid = threadIdx.x;
  const int blk = blockIdx.x;
  const int b  = blk >> 9;                // 512 blocks / batch
  const int pg = (blk >> 1) & 255;        // 4-pixel group
  const int cg = blk & 1;                 // channel group: channels cg*8..+7
  for (int idx = tid; idx < 25 * 8; idx += 256) {
    const int co = idx & 7, kk = idx >> 3;
    const float w = wt[(cg * 8 + co) * 25 + kk];
    wlds[idx] = w;                        // lds[kk*8+co]
    const __fp16 wh = (__fp16)w;
    h2 wp; wp.x = wh; wp.y = wh;
    whds[idx] = wp;
  }
  __syncthreads();
  const int pl = tid >> 6, lane = tid & 63;
  const int pixel = pg * 4 + pl;
  const int h_ = pixel >> 5, w_ = pixel & 31;

  // d_out zero (common-case final answer; rare_chain overwrites if spikes)
  if (cg == 0) {
    *(float4*)(dout + (size_t)(b * 1024 + pixel) * 256 + lane * 4) =
        make_float4(0.f, 0.f, 0.f, 0.f);
  }

  const float* inb = in + (size_t)b * H * W * 256;

  // ---- common path: packed-f16 conv (2 FMA/instr) ----
  h2 accL[8], accH[8];
#pragma unroll
  for (int c = 0; c < 8; ++c) {
    h2 z; z.x = (__fp16)0.f; z.y = (__fp16)0.f;
    accL[c] = z; accH[c] = z;
  }
#pragma unroll
  for (int kh = 0; kh < K; ++kh) {
    const int hh = h_ + kh - P;
    if (hh < 0 || hh >= H) continue;      // wave-uniform (lanes share pixel)
    float4 xr[5];
#pragma unroll
    for (int kw = 0; kw < K; ++kw) {
      const int ww = w_ + kw - P;
      xr[kw] = (ww >= 0 && ww < W)
                 ? *(const float4*)(inb + (size_t)(hh * W + ww) * 256 + lane * 4)
                 : make_float4(0.f, 0.f, 0.f, 0.f);
    }
#pragma unroll
    for (int kw = 0; kw < K; ++kw) {
      const float4 x = xr[kw];
      const h2 xlo = __builtin_amdgcn_cvt_pkrtz(x.x, x.y);  // binary: exact
      const h2 xhi = __builtin_amdgcn_cvt_pkrtz(x.z, x.w);
      const h2* wr = &whds[(kh * K + kw) * 8];
#pragma unroll
      for (int c = 0; c < 8; ++c) {
        const h2 wv = wr[c];
        accL[c] = accL[c] + wv * xlo;     // v_pk_fma_f16
        accH[c] = accH[c] + wv * xhi;
      }
    }
  }
  // Combined a-priori bound over this block's 8 channels (f16 + eps guard).
  float mxa = 0.f;
#pragma unroll
  for (int c = 0; c < 8; ++c) {
    mxa = fmaxf(mxa, fmaxf(fmaxf(fabsf((float)accL[c].x), fabsf((float)accL[c].y)),
                           fmaxf(fabsf((float)accH[c].x), fabsf((float)accH[c].y))));
  }
#pragma unroll
  for (int d = 1; d < 64; d <<= 1) mxa = fmaxf(mxa, __shfl_xor(mxa, d, 64));
  if (PSPBND * (mxa + F16EPS) < THETA) return;  // wave-uniform: cannot spike

  // ---- rare path (~1.3% of waves): EXACT fp32 conv, then bound/scan/dump ----
  float4 acc[8];
#pragma unroll
  for (int c = 0; c < 8; ++c) acc[c] = make_float4(0.f, 0.f, 0.f, 0.f);
#pragma unroll
  for (int kh = 0; kh < K; ++kh) {
    const int hh = h_ + kh - P;
    if (hh < 0 || hh >= H) continue;
    float4 xr[5];
#pragma unroll
    for (int kw = 0; kw < K; ++kw) {
      const int ww = w_ + kw - P;
      xr[kw] = (ww >= 0 && ww < W)
                 ? *(const float4*)(inb + (size_t)(hh * W + ww) * 256 + lane * 4)
                 : make_float4(0.f, 0.f, 0.f, 0.f);
    }
#pragma unroll
    for (int kw = 0; kw < K; ++kw) {
      const float4 x = xr[kw];
      const float4* wr = (const float4*)&wlds[(kh * K + kw) * 8];
#pragma unroll
      for (int c4 = 0; c4 < 2; ++c4) {
        const float4 wv = wr[c4];
        acc[4*c4+0].x += x.x * wv.x; acc[4*c4+0].y += x.y * wv.x;
        acc[4*c4+0].z += x.z * wv.x; acc[4*c4+0].w += x.w * wv.x;
        acc[4*c4+1].x += x.x * wv.y; acc[4*c4+1].y += x.y * wv.y;
        acc[4*c4+1].z += x.z * wv.y; acc[4*c4+1].w += x.w * wv.y;
        acc[4*c4+2].x += x.x * wv.z; acc[4*c4+2].y += x.y * wv.z;
        acc[4*c4+2].z += x.z * wv.z; acc[4*c4+2].w += x.w * wv.z;
        acc[4*c4+3].x += x.x * wv.w; acc[4*c4+3].y += x.y * wv.w;
        acc[4*c4+3].z += x.z * wv.w; acc[4*c4+3].w += x.w * wv.w;
      }
    }
  }
  // Per-channel bound, then exact scan only where needed (FULLY UNROLLED).
#pragma unroll
  for (int c = 0; c < 8; ++c) {
    float mc = fmaxf(fmaxf(fabsf(acc[c].x), fabsf(acc[c].y)),
                     fmaxf(fabsf(acc[c].z), fabsf(acc[c].w)));
#pragma unroll
    for (int d = 1; d < 64; d <<= 1) mc = fmaxf(mc, __shfl_xor(mc, d, 64));
    if (PSPBND * mc >= THETA) {           // wave-uniform
      const float x0 = acc[c].x, x1 = acc[c].y, x2 = acc[c].z, x3 = acc[c].w;
      float g1 = x0, g2 = x0;             // local 4-step from zero state
      g1 = D_SR * g1 + x1; g2 = D_SR * g2 + g1;
      g1 = D_SR * g1 + x2; g2 = D_SR * g2 + g1;
      g1 = D_SR * g1 + x3; g2 = D_SR * g2 + g1;
      float s1v = g1, s2v = g2;           // inclusive KS scan (6 steps)
      SCANSTEP(1,  0.67032004603563930f,   4.f)
      SCANSTEP(2,  0.44932896411722156f,   8.f)
      SCANSTEP(4,  0.20189651799465538f,   16.f)
      SCANSTEP(8,  0.040762203978366215f,  32.f)
      SCANSTEP(16, 0.0016615572731739338f, 64.f)
      SCANSTEP(32, 2.7607725720371994e-06f, 128.f)
      float p1 = __shfl_up(s1v, 1, 64);   // exclusive seed
      float p2 = __shfl_up(s2v, 1, 64);
      if (lane == 0) { p1 = 0.f; p2 = 0.f; }
      float h1 = D_SR * p1 + x0, hh2 = D_SR * p2 + h1;
      const float a0 = PSPSC * (hh2 - h1);
      h1 = D_SR * h1 + x1; hh2 = D_SR * hh2 + h1;
      const float a1 = PSPSC * (hh2 - h1);
      h1 = D_SR * h1 + x2; hh2 = D_SR * hh2 + h1;
      const float a2 = PSPSC * (hh2 - h1);
      h1 = D_SR * h1 + x3; hh2 = D_SR * hh2 + h1;
      const float a3 = PSPSC * (hh2 - h1);
      const float mx = fmaxf(fmaxf(a0, a1), fmaxf(a2, a3));
      if (__any((int)(mx >= THETA))) {    // exact: row has >=1 spike
        const int cglob = cg * 8 + c;
        *(float4*)(Vr + ((size_t)(b * 16 + cglob) * 1024 + pixel) * 256 + lane * 4)
            = make_float4(a0, a1, a2, a3);
        if (lane == 0) {
          dpix[(b * 16 + cglob) * 1024 + pixel] = 1;
          dirty[b * 16 + cglob] = 1u;
        }
      }
    }
  }
}
#undef SCANSTEP

// ---------------------------------------------------------------------------
// rare_chain: single-block exact recompute of L2..L9 when any L1 channel
// spiked. Common case: reads 64 dirty flags, exits in ~1 us. When active:
// straightforward fp32 reference-equivalent loops, __syncthreads between
// stages, all intermediates in ws. Slow but correct; never executes here.
// ---------------------------------------------------------------------------
__global__ __launch_bounds__(256)
void rare_chain(const float* __restrict__ Vr, const unsigned char* __restrict__ dpix,
                const unsigned* __restrict__ dirty,
                const float* __restrict__ w2, const float* __restrict__ w3,
                const float* __restrict__ w4, const float* __restrict__ wout,
                unsigned char* __restrict__ S1, unsigned char* __restrict__ S2,
                unsigned char* __restrict__ S3, unsigned char* __restrict__ S4,
                unsigned char* __restrict__ S5, unsigned char* __restrict__ S6,
                unsigned char* __restrict__ S7, unsigned char* __restrict__ S8,
                float* __restrict__ out) {
  unsigned any = 0;
  for (int i = 0; i < 64; ++i) any |= (dirty[i] == 1u) ? 1u : 0u;
  if (!any) return;                       // uniform fast exit (common)
  const int tid = threadIdx.x;

  // A: s1 spikes from dumped membranes (non-dumped rows provably spike-free)
  for (int r = tid; r < 65536; r += 256) {
    unsigned char* o = S1 + (size_t)r * 256;
    if (dpix[r] == 1) {
      const float* a = Vr + (size_t)r * 256;
      float rr = 0.f;
      for (int t = 0; t < 256; ++t) {
        const float u = a[t] + rr - THETA;
        const int s = (u >= 0.f) ? 1 : 0;
        rr = D_REF * (rr - REFSC * (float)s);
        o[t] = (unsigned char)s;
      }
    } else {
      for (int t = 0; t < 256; ++t) o[t] = 0;
    }
  }
  __syncthreads();
  // B: s2 = spike(psp(pool(s1))) [4,16,16,16]
  for (int r = tid; r < 16384; r += 256) {
    const int pw = r & 15, ph = (r >> 4) & 15, bc = r >> 8;
    const unsigned char* q0 = S1 + ((size_t)(bc * 1024 + (2 * ph) * 32 + 2 * pw)) * 256;
    const unsigned char* q1 = q0 + 256;
    const unsigned char* q2 = q0 + 32 * 256;
    const unsigned char* q3 = q2 + 256;
    unsigned char* o = S2 + (size_t)r * 256;
    float g1 = 0, g2 = 0, rr = 0;
    for (int t = 0; t < 256; ++t)
      o[t] = (unsigned char)snstep_i((float)(q0[t] + q1[t] + q2[t] + q3[t]) * POOLSC,
                                     g1, g2, rr);
  }
  __syncthreads();
  // C: s3 = spike(psp(conv3x3 16->32 (s2))) @16x16
  for (int r = tid; r < 32768; r += 256) {
    const int w_ = r & 15, h_ = (r >> 4) & 15;
    const int co = (r >> 8) & 31, b = r >> 13;
    unsigned char* o = S3 + (size_t)r * 256;
    float g1 = 0, g2 = 0, rr = 0;
    for (int t = 0; t < 256; ++t) {
      float acc = 0.f;
      for (int ci = 0; ci < 16; ++ci)
        for (int kh = 0; kh < 3; ++kh) {
          const int hh = h_ + kh - 1; if (hh < 0 || hh >= 16) continue;
          for (int kw = 0; kw < 3; ++kw) {
            const int ww = w_ + kw - 1; if (ww < 0 || ww >= 16) continue;
            acc += w2[((co * 16 + ci) * 3 + kh) * 3 + kw] *
                   (float)S2[((size_t)((b * 16 + ci) * 256 + hh * 16 + ww)) * 256 + t];
          }
        }
      o[t] = (unsigned char)snstep_i(acc, g1, g2, rr);
    }
  }
  __syncthreads();
  // D: s4 = spike(psp(pool(s3))) [4,32,8,8]
  for (int r = tid; r < 8192; r += 256) {
    const int pw = r & 7, ph = (r >> 3) & 7, bc = r >> 6;
    const unsigned char* q0 = S3 + ((size_t)(bc * 256 + (2 * ph) * 16 + 2 * pw)) * 256;
    const unsigned char* q1 = q0 + 256;
    const unsigned char* q2 = q0 + 16 * 256;
    const unsigned char* q3 = q2 + 256;
    unsigned char* o = S4 + (size_t)r * 256;
    float g1 = 0, g2 = 0, rr = 0;
    for (int t = 0; t < 256; ++t)
      o[t] = (unsigned char)snstep_i((float)(q0[t] + q1[t] + q2[t] + q3[t]) * POOLSC,
                                     g1, g2, rr);
  }
  __syncthreads();
  // E: s5 = spike(psp(conv3x3 32->64 (s4))) @8x8
  for (int r = tid; r < 16384; r += 256) {
    const int w_ = r & 7, h_ = (r >> 3) & 7;
    const int co = (r >> 6) & 63, b = r >> 12;
    unsigned char* o = S5 + (size_t)r * 256;
    float g1 = 0, g2 = 0, rr = 0;
    for (int t = 0; t < 256; ++t) {
      float acc = 0.f;
      for (int ci = 0; ci < 32; ++ci)
        for (int kh = 0; kh < 3; ++kh) {
          const int hh = h_ + kh - 1; if (hh < 0 || hh >= 8) continue;
          for (int kw = 0; kw < 3; ++kw) {
            const int ww = w_ + kw - 1; if (ww < 0 || ww >= 8) continue;
            acc += w3[((co * 32 + ci) * 3 + kh) * 3 + kw] *
                   (float)S4[((size_t)((b * 32 + ci) * 64 + hh * 8 + ww)) * 256 + t];
          }
        }
      o[t] = (unsigned char)snstep_i(acc, g1, g2, rr);
    }
  }
  __syncthreads();
  // F: s6 = spike(psp(up2(s5))) [4,64,16,16]
  for (int r = tid; r < 65536; r += 256) {
    const int ow = r & 15, oh = (r >> 4) & 15, bc = r >> 8;
    int h0, h1, w0, w1; float fh0, fh1, fw0, fw1;
    upcoef(oh, 8, h0, h1, fh0, fh1);
    upcoef(ow, 8, w0, w1, fw0, fw1);
    const float c00 = fh0 * fw0, c01 = fh0 * fw1, c10 = fh1 * fw0, c11 = fh1 * fw1;
    const unsigned char* q00 = S5 + ((size_t)(bc * 64 + h0 * 8 + w0)) * 256;
    const unsigned char* q01 = S5 + ((size_t)(bc * 64 + h0 * 8 + w1)) * 256;
    const unsigned char* q10 = S5 + ((size_t)(bc * 64 + h1 * 8 + w0)) * 256;
    const unsigned char* q11 = S5 + ((size_t)(bc * 64 + h1 * 8 + w1)) * 256;
    unsigned char* o = S6 + (size_t)r * 256;
    float g1 = 0, g2 = 0, rr = 0;
    for (int t = 0; t < 256; ++t)
      o[t] = (unsigned char)snstep_i(
          c00 * q00[t] + c01 * q01[t] + c10 * q10[t] + c11 * q11[t], g1, g2, rr);
  }
  __syncthreads();
  // G: s7 = spike(psp(conv3x3 64->32 (s6))) @16x16
  for (int r = tid; r < 32768; r += 256) {
    const int w_ = r & 15, h_ = (r >> 4) & 15;
    const int co = (r >> 8) & 31, b = r >> 13;
    unsigned char* o = S7 + (size_t)r * 256;
    float g1 = 0, g2 = 0, rr = 0;
    for (int t = 0; t < 256; ++t) {
      float acc = 0.f;
      for (int ci = 0; ci < 64; ++ci)
        for (int kh = 0; kh < 3; ++kh) {
          const int hh = h_ + kh - 1; if (hh < 0 || hh >= 16) continue;
          for (int kw = 0; kw < 3; ++kw) {
            const int ww = w_ + kw - 1; if (ww < 0 || ww >= 16) continue;
            acc += w4[((co * 64 + ci) * 3 + kh) * 3 + kw] *
                   (float)S6[((size_t)((b * 64 + ci) * 256 + hh * 16 + ww)) * 256 + t];
          }
        }
      o[t] = (unsigned char)snstep_i(acc, g1, g2, rr);
    }
  }
  __syncthreads();
  // H: s8 = spike(psp(up2(s7))) [4,32,32,32]
  for (int r = tid; r < 131072; r += 256) {
    const int ow = r & 31, oh = (r >> 5) & 31, bc = r >> 10;
    int h0, h1, w0, w1; float fh0, fh1, fw0, fw1;
    upcoef(oh, 16, h0, h1, fh0, fh1);
    upcoef(ow, 16, w0, w1, fw0, fw1);
    const float c00 = fh0 * fw0, c01 = fh0 * fw1, c10 = fh1 * fw0, c11 = fh1 * fw1;
    const unsigned char* q00 = S7 + ((size_t)(bc * 256 + h0 * 16 + w0)) * 256;
    const unsigned char* q01 = S7 + ((size_t)(bc * 256 + h0 * 16 + w1)) * 256;
    const unsigned char* q10 = S7 + ((size_t)(bc * 256 + h1 * 16 + w0)) * 256;
    const unsigned char* q11 = S7 + ((size_t)(bc * 256 + h1 * 16 + w1)) * 256;
    unsigned char* o = S8 + (size_t)r * 256;
    float g1 = 0, g2 = 0, rr = 0;
    for (int t = 0; t < 256; ++t)
      o[t] = (unsigned char)snstep_i(
          c00 * q00[t] + c01 * q01[t] + c10 * q10[t] + c11 * q11[t], g1, g2, rr);
  }
  __syncthreads();
  // I: out = spike(psp(conv1x1 32->1 (s8))) -- overwrites pre-zeroed d_out
  for (int r = tid; r < 4096; r += 256) {
    const int b = r >> 10, pix = r & 1023;
    float* o = out + (size_t)r * 256;
    float g1 = 0, g2 = 0, rr = 0;
    for (int t = 0; t < 256; ++t) {
      float acc = 0.f;
      for (int c = 0; c < 32; ++c)
        acc += wout[c] * (float)S8[((size_t)((b * 32 + c) * 1024 + pix)) * 256 + t];
      o[t] = snstep(acc, g1, g2, rr);
    }
  }
}

// ---------------------------------------------------------------------------
// Orchestration: 2 launches. l1_fused (f16 common path + exact fp32 rare
// path) decides spike-existence and writes the common-case zero output;
// rare_chain exits immediately unless L1 spiked, else recomputes L2..L9.
// ws map (256 MiB): Vr f32 @0 (64M) | S1@64M S2@81M S3@86M S4@95M S5@98M
// S6@103M S7@120M S8@129M (rare-path u8 spike buffers) | dpix@168M dirty@169M.
// ---------------------------------------------------------------------------
extern "C" void kernel_launch(void* const* d_in, const int* in_sizes, int n_in,
                              void* d_out, int out_size, void* d_ws, size_t ws_size,
                              hipStream_t stream) {
  const float* x    = (const float*)d_in[0];
  const float* w1   = (const float*)d_in[1];
  const float* w2   = (const float*)d_in[2];
  const float* w3   = (const float*)d_in[3];
  const float* w4   = (const float*)d_in[4];
  const float* wout = (const float*)d_in[5];
  char* ws = (char*)d_ws;
  float*         Vr = (float*)(ws);
  unsigned char* S1 = (unsigned char*)(ws + ((size_t)64  << 20));
  unsigned char* S2 = (unsigned char*)(ws + ((size_t)81  << 20));
  unsigned char* S3 = (unsigned char*)(ws + ((size_t)86  << 20));
  unsigned char* S4 = (unsigned char*)(ws + ((size_t)95  << 20));
  unsigned char* S5 = (unsigned char*)(ws + ((size_t)98  << 20));
  unsigned char* S6 = (unsigned char*)(ws + ((size_t)103 << 20));
  unsigned char* S7 = (unsigned char*)(ws + ((size_t)120 << 20));
  unsigned char* S8 = (unsigned char*)(ws + ((size_t)129 << 20));
  unsigned char* dpix = (unsigned char*)(ws + ((size_t)168 << 20));
  unsigned*      dirty = (unsigned*)(ws + ((size_t)169 << 20));
  float* out = (float*)d_out;

  // L1: f16 conv + existence bound (exact fp32 fallback); rare rows -> Vr
  l1_fused<<<2048, 256, 0, stream>>>(x, w1, Vr, dpix, dirty, out);
  // Gated exact recompute of the whole downstream (normally exits at once)
  rare_chain<<<1, 256, 0, stream>>>(Vr, dpix, dirty, w2, w3, w4, wout,
                                    S1, S2, S3, S4, S5, S6, S7, S8, out);
}

// Round 15
// 85.497 us; speedup vs baseline: 1.0874x; 1.0874x over previous
//
#include <hip/hip_runtime.h>

// SLAYER SRM-alpha constants (fp32-rounded from the reference doubles)
#define D_SR   0.90483741803595952f   // exp(-1/10)
#define D_REF  0.36787944117144233f   // exp(-1)
#define PSPSC  0.27182818284590454f   // e/10
#define THETA  10.0f
#define REFSC  20.0f                  // scaleRef * theta
#define POOLSC 2.75f                  // 1.1*theta/4
// Safe upper bound on the psp gain sum (e/10)*sum_{s} s*d^s = 27.160...
#define PSPBND 27.2f

// One SRM step: two cascaded IIR stages (alpha PSP), threshold, exp refractory.
__device__ __forceinline__ float snstep(float x, float& g1, float& g2, float& r) {
  g1 = D_SR * g1 + x;
  g2 = D_SR * g2 + g1;
  const float u = PSPSC * (g2 - g1) + r - THETA;
  const float s = (u >= 0.0f) ? 1.0f : 0.0f;
  r = D_REF * (r - REFSC * s);
  return s;
}

__device__ __forceinline__ int snstep_i(float x, float& g1, float& g2, float& r) {
  g1 = D_SR * g1 + x;
  g2 = D_SR * g2 + g1;
  const float u = PSPSC * (g2 - g1) + r - THETA;
  const int s = (u >= 0.0f) ? 1 : 0;
  r = D_REF * (r - REFSC * (float)s);
  return s;
}

// jax.image.resize bilinear 2x coeffs (clamped): validated absmax=0 R0-R14.
__device__ __forceinline__ void upcoef(int o, int I, int& i0, int& i1,
                                       float& f0, float& f1) {
  const int k = o >> 1;
  if (o & 1) { i0 = k; i1 = (k + 1 < I) ? k + 1 : I - 1; f0 = 0.75f; f1 = 0.25f; }
  else       { i0 = (k > 0) ? k - 1 : 0; i1 = k;         f0 = 0.25f; f1 = 0.75f; }
}

// ---------------------------------------------------------------------------
// L1 fused: conv5x5 (Ci=1) + psp + spike-existence + d_out zero.
// R15: REVERT the f16 experiment (R14: 93.0 us vs fp32 R12: 83.8 us) and
// extend the validated channel-split lever 8 -> 4 channels/block
// (cg = blk&3): per-thread FMA 800->400, acc 32->16 VGPR, same 25 loads.
// Wave = one pixel's full T (lane = 4-step t-segment).
// Existence: r<=0 invariant => spike iff max_t a_t >= theta;
// |a_t| <= PSPBND*max|v| gives the cheap wave-uniform common-case exit.
// Rare: per-channel bound -> exact Kogge-Stone psp scan -> existence ->
// dump membrane to Vr + dpix/dirty for rare_chain.
// NOTE (R9 lesson): every loop touching acc[] MUST be fully unrolled —
// rolled loops dynamically index acc[] and demote it to scratch.
// Flags use ==1u semantics (0xAA ws-poison reads as unset -> no init).
// ---------------------------------------------------------------------------
#define SCANSTEP(DELTA, CK, MK)                                         \
  { float o1 = __shfl_up(s1v, DELTA, 64);                               \
    float o2 = __shfl_up(s2v, DELTA, 64);                               \
    if (lane < DELTA) { o1 = 0.f; o2 = 0.f; }                           \
    s2v = fmaf(CK, fmaf(MK, o1, o2), s2v);                              \
    s1v = fmaf(CK, o1, s1v); }

__global__ __launch_bounds__(256)
void l1_fused(const float* __restrict__ in, const float* __restrict__ wt,
              float* __restrict__ Vr, unsigned char* __restrict__ dpix,
              unsigned* __restrict__ dirty, float* __restrict__ dout) {
  const int H = 32, W = 32, K = 5, P = 2;
  __shared__ float wlds[25 * 4];
  const int tid = threadIdx.x;
  const int blk = blockIdx.x;
  const int b  = blk >> 10;               // 1024 blocks / batch
  const int pg = (blk >> 2) & 255;        // 4-pixel group
  const int cg = blk & 3;                 // channel group: channels cg*4..+3
  for (int idx = tid; idx < 25 * 4; idx += 256) {
    const int co = idx & 3, kk = idx >> 2;
    wlds[idx] = wt[(cg * 4 + co) * 25 + kk];   // lds[kk*4+co]
  }
  __syncthreads();
  const int pl = tid >> 6, lane = tid & 63;
  const int pixel = pg * 4 + pl;
  const int h_ = pixel >> 5, w_ = pixel & 31;

  // d_out zero (common-case final answer; rare_chain overwrites if spikes)
  if (cg == 0) {
    *(float4*)(dout + (size_t)(b * 1024 + pixel) * 256 + lane * 4) =
        make_float4(0.f, 0.f, 0.f, 0.f);
  }

  float4 acc[4];
#pragma unroll
  for (int c = 0; c < 4; ++c) acc[c] = make_float4(0.f, 0.f, 0.f, 0.f);
  const float* inb = in + (size_t)b * H * W * 256;
#pragma unroll
  for (int kh = 0; kh < K; ++kh) {
    const int hh = h_ + kh - P;
    if (hh < 0 || hh >= H) continue;      // wave-uniform (lanes share pixel)
    float4 xr[5];
#pragma unroll
    for (int kw = 0; kw < K; ++kw) {
      const int ww = w_ + kw - P;
      xr[kw] = (ww >= 0 && ww < W)
                 ? *(const float4*)(inb + (size_t)(hh * W + ww) * 256 + lane * 4)
                 : make_float4(0.f, 0.f, 0.f, 0.f);
    }
#pragma unroll
    for (int kw = 0; kw < K; ++kw) {
      const float4 x = xr[kw];
      const float4 wv = *(const float4*)&wlds[(kh * K + kw) * 4];
      acc[0].x += x.x * wv.x; acc[0].y += x.y * wv.x;
      acc[0].z += x.z * wv.x; acc[0].w += x.w * wv.x;
      acc[1].x += x.x * wv.y; acc[1].y += x.y * wv.y;
      acc[1].z += x.z * wv.y; acc[1].w += x.w * wv.y;
      acc[2].x += x.x * wv.z; acc[2].y += x.y * wv.z;
      acc[2].z += x.z * wv.z; acc[2].w += x.w * wv.z;
      acc[3].x += x.x * wv.w; acc[3].y += x.y * wv.w;
      acc[3].z += x.z * wv.w; acc[3].w += x.w * wv.w;
    }
  }

  // Combined a-priori bound over this block's 4 channels: one wave reduce.
  float mxa = 0.f;
#pragma unroll
  for (int c = 0; c < 4; ++c) {
    mxa = fmaxf(mxa, fmaxf(fmaxf(fabsf(acc[c].x), fabsf(acc[c].y)),
                           fmaxf(fabsf(acc[c].z), fabsf(acc[c].w))));
  }
#pragma unroll
  for (int d = 1; d < 64; d <<= 1) mxa = fmaxf(mxa, __shfl_xor(mxa, d, 64));
  if (PSPBND * mxa < THETA) return;       // wave-uniform: no channel can spike

  // Rare: per-channel bound, then exact scan only where needed.
  // FULLY UNROLLED so acc[] stays in registers (R9 lesson).
#pragma unroll
  for (int c = 0; c < 4; ++c) {
    float mc = fmaxf(fmaxf(fabsf(acc[c].x), fabsf(acc[c].y)),
                     fmaxf(fabsf(acc[c].z), fabsf(acc[c].w)));
#pragma unroll
    for (int d = 1; d < 64; d <<= 1) mc = fmaxf(mc, __shfl_xor(mc, d, 64));
    if (PSPBND * mc >= THETA) {           // wave-uniform
      const float x0 = acc[c].x, x1 = acc[c].y, x2 = acc[c].z, x3 = acc[c].w;
      float g1 = x0, g2 = x0;             // local 4-step from zero state
      g1 = D_SR * g1 + x1; g2 = D_SR * g2 + g1;
      g1 = D_SR * g1 + x2; g2 = D_SR * g2 + g1;
      g1 = D_SR * g1 + x3; g2 = D_SR * g2 + g1;
      float s1v = g1, s2v = g2;           // inclusive KS scan (6 steps)
      SCANSTEP(1,  0.67032004603563930f,   4.f)
      SCANSTEP(2,  0.44932896411722156f,   8.f)
      SCANSTEP(4,  0.20189651799465538f,   16.f)
      SCANSTEP(8,  0.040762203978366215f,  32.f)
      SCANSTEP(16, 0.0016615572731739338f, 64.f)
      SCANSTEP(32, 2.7607725720371994e-06f, 128.f)
      float p1 = __shfl_up(s1v, 1, 64);   // exclusive seed
      float p2 = __shfl_up(s2v, 1, 64);
      if (lane == 0) { p1 = 0.f; p2 = 0.f; }
      float h1 = D_SR * p1 + x0, h2 = D_SR * p2 + h1;
      const float a0 = PSPSC * (h2 - h1);
      h1 = D_SR * h1 + x1; h2 = D_SR * h2 + h1;
      const float a1 = PSPSC * (h2 - h1);
      h1 = D_SR * h1 + x2; h2 = D_SR * h2 + h1;
      const float a2 = PSPSC * (h2 - h1);
      h1 = D_SR * h1 + x3; h2 = D_SR * h2 + h1;
      const float a3 = PSPSC * (h2 - h1);
      const float mx = fmaxf(fmaxf(a0, a1), fmaxf(a2, a3));
      if (__any((int)(mx >= THETA))) {    // exact: row has >=1 spike
        const int cglob = cg * 4 + c;
        *(float4*)(Vr + ((size_t)(b * 16 + cglob) * 1024 + pixel) * 256 + lane * 4)
            = make_float4(a0, a1, a2, a3);
        if (lane == 0) {
          dpix[(b * 16 + cglob) * 1024 + pixel] = 1;
          dirty[b * 16 + cglob] = 1u;
        }
      }
    }
  }
}
#undef SCANSTEP

// ---------------------------------------------------------------------------
// rare_chain: single-block exact recompute of L2..L9 when any L1 channel
// spiked. Common case: reads 64 dirty flags, exits in ~1 us. When active:
// straightforward fp32 reference-equivalent loops, __syncthreads between
// stages, all intermediates in ws. Slow but correct; never executes here.
// ---------------------------------------------------------------------------
__global__ __launch_bounds__(256)
void rare_chain(const float* __restrict__ Vr, const unsigned char* __restrict__ dpix,
                const unsigned* __restrict__ dirty,
                const float* __restrict__ w2, const float* __restrict__ w3,
                const float* __restrict__ w4, const float* __restrict__ wout,
                unsigned char* __restrict__ S1, unsigned char* __restrict__ S2,
                unsigned char* __restrict__ S3, unsigned char* __restrict__ S4,
                unsigned char* __restrict__ S5, unsigned char* __restrict__ S6,
                unsigned char* __restrict__ S7, unsigned char* __restrict__ S8,
                float* __restrict__ out) {
  unsigned any = 0;
  for (int i = 0; i < 64; ++i) any |= (dirty[i] == 1u) ? 1u : 0u;
  if (!any) return;                       // uniform fast exit (common)
  const int tid = threadIdx.x;

  // A: s1 spikes from dumped membranes (non-dumped rows provably spike-free)
  for (int r = tid; r < 65536; r += 256) {
    unsigned char* o = S1 + (size_t)r * 256;
    if (dpix[r] == 1) {
      const float* a = Vr + (size_t)r * 256;
      float rr = 0.f;
      for (int t = 0; t < 256; ++t) {
        const float u = a[t] + rr - THETA;
        const int s = (u >= 0.f) ? 1 : 0;
        rr = D_REF * (rr - REFSC * (float)s);
        o[t] = (unsigned char)s;
      }
    } else {
      for (int t = 0; t < 256; ++t) o[t] = 0;
    }
  }
  __syncthreads();
  // B: s2 = spike(psp(pool(s1))) [4,16,16,16]
  for (int r = tid; r < 16384; r += 256) {
    const int pw = r & 15, ph = (r >> 4) & 15, bc = r >> 8;
    const unsigned char* q0 = S1 + ((size_t)(bc * 1024 + (2 * ph) * 32 + 2 * pw)) * 256;
    const unsigned char* q1 = q0 + 256;
    const unsigned char* q2 = q0 + 32 * 256;
    const unsigned char* q3 = q2 + 256;
    unsigned char* o = S2 + (size_t)r * 256;
    float g1 = 0, g2 = 0, rr = 0;
    for (int t = 0; t < 256; ++t)
      o[t] = (unsigned char)snstep_i((float)(q0[t] + q1[t] + q2[t] + q3[t]) * POOLSC,
                                     g1, g2, rr);
  }
  __syncthreads();
  // C: s3 = spike(psp(conv3x3 16->32 (s2))) @16x16
  for (int r = tid; r < 32768; r += 256) {
    const int w_ = r & 15, h_ = (r >> 4) & 15;
    const int co = (r >> 8) & 31, b = r >> 13;
    unsigned char* o = S3 + (size_t)r * 256;
    float g1 = 0, g2 = 0, rr = 0;
    for (int t = 0; t < 256; ++t) {
      float acc = 0.f;
      for (int ci = 0; ci < 16; ++ci)
        for (int kh = 0; kh < 3; ++kh) {
          const int hh = h_ + kh - 1; if (hh < 0 || hh >= 16) continue;
          for (int kw = 0; kw < 3; ++kw) {
            const int ww = w_ + kw - 1; if (ww < 0 || ww >= 16) continue;
            acc += w2[((co * 16 + ci) * 3 + kh) * 3 + kw] *
                   (float)S2[((size_t)((b * 16 + ci) * 256 + hh * 16 + ww)) * 256 + t];
          }
        }
      o[t] = (unsigned char)snstep_i(acc, g1, g2, rr);
    }
  }
  __syncthreads();
  // D: s4 = spike(psp(pool(s3))) [4,32,8,8]
  for (int r = tid; r < 8192; r += 256) {
    const int pw = r & 7, ph = (r >> 3) & 7, bc = r >> 6;
    const unsigned char* q0 = S3 + ((size_t)(bc * 256 + (2 * ph) * 16 + 2 * pw)) * 256;
    const unsigned char* q1 = q0 + 256;
    const unsigned char* q2 = q0 + 16 * 256;
    const unsigned char* q3 = q2 + 256;
    unsigned char* o = S4 + (size_t)r * 256;
    float g1 = 0, g2 = 0, rr = 0;
    for (int t = 0; t < 256; ++t)
      o[t] = (unsigned char)snstep_i((float)(q0[t] + q1[t] + q2[t] + q3[t]) * POOLSC,
                                     g1, g2, rr);
  }
  __syncthreads();
  // E: s5 = spike(psp(conv3x3 32->64 (s4))) @8x8
  for (int r = tid; r < 16384; r += 256) {
    const int w_ = r & 7, h_ = (r >> 3) & 7;
    const int co = (r >> 6) & 63, b = r >> 12;
    unsigned char* o = S5 + (size_t)r * 256;
    float g1 = 0, g2 = 0, rr = 0;
    for (int t = 0; t < 256; ++t) {
      float acc = 0.f;
      for (int ci = 0; ci < 32; ++ci)
        for (int kh = 0; kh < 3; ++kh) {
          const int hh = h_ + kh - 1; if (hh < 0 || hh >= 8) continue;
          for (int kw = 0; kw < 3; ++kw) {
            const int ww = w_ + kw - 1; if (ww < 0 || ww >= 8) continue;
            acc += w3[((co * 32 + ci) * 3 + kh) * 3 + kw] *
                   (float)S4[((size_t)((b * 32 + ci) * 64 + hh * 8 + ww)) * 256 + t];
          }
        }
      o[t] = (unsigned char)snstep_i(acc, g1, g2, rr);
    }
  }
  __syncthreads();
  // F: s6 = spike(psp(up2(s5))) [4,64,16,16]
  for (int r = tid; r < 65536; r += 256) {
    const int ow = r & 15, oh = (r >> 4) & 15, bc = r >> 8;
    int h0, h1, w0, w1; float fh0, fh1, fw0, fw1;
    upcoef(oh, 8, h0, h1, fh0, fh1);
    upcoef(ow, 8, w0, w1, fw0, fw1);
    const float c00 = fh0 * fw0, c01 = fh0 * fw1, c10 = fh1 * fw0, c11 = fh1 * fw1;
    const unsigned char* q00 = S5 + ((size_t)(bc * 64 + h0 * 8 + w0)) * 256;
    const unsigned char* q01 = S5 + ((size_t)(bc * 64 + h0 * 8 + w1)) * 256;
    const unsigned char* q10 = S5 + ((size_t)(bc * 64 + h1 * 8 + w0)) * 256;
    const unsigned char* q11 = S5 + ((size_t)(bc * 64 + h1 * 8 + w1)) * 256;
    unsigned char* o = S6 + (size_t)r * 256;
    float g1 = 0, g2 = 0, rr = 0;
    for (int t = 0; t < 256; ++t)
      o[t] = (unsigned char)snstep_i(
          c00 * q00[t] + c01 * q01[t] + c10 * q10[t] + c11 * q11[t], g1, g2, rr);
  }
  __syncthreads();
  // G: s7 = spike(psp(conv3x3 64->32 (s6))) @16x16
  for (int r = tid; r < 32768; r += 256) {
    const int w_ = r & 15, h_ = (r >> 4) & 15;
    const int co = (r >> 8) & 31, b = r >> 13;
    unsigned char* o = S7 + (size_t)r * 256;
    float g1 = 0, g2 = 0, rr = 0;
    for (int t = 0; t < 256; ++t) {
      float acc = 0.f;
      for (int ci = 0; ci < 64; ++ci)
        for (int kh = 0; kh < 3; ++kh) {
          const int hh = h_ + kh - 1; if (hh < 0 || hh >= 16) continue;
          for (int kw = 0; kw < 3; ++kw) {
            const int ww = w_ + kw - 1; if (ww < 0 || ww >= 16) continue;
            acc += w4[((co * 64 + ci) * 3 + kh) * 3 + kw] *
                   (float)S6[((size_t)((b * 64 + ci) * 256 + hh * 16 + ww)) * 256 + t];
          }
        }
      o[t] = (unsigned char)snstep_i(acc, g1, g2, rr);
    }
  }
  __syncthreads();
  // H: s8 = spike(psp(up2(s7))) [4,32,32,32]
  for (int r = tid; r < 131072; r += 256) {
    const int ow = r & 31, oh = (r >> 5) & 31, bc = r >> 10;
    int h0, h1, w0, w1; float fh0, fh1, fw0, fw1;
    upcoef(oh, 16, h0, h1, fh0, fh1);
    upcoef(ow, 16, w0, w1, fw0, fw1);
    const float c00 = fh0 * fw0, c01 = fh0 * fw1, c10 = fh1 * fw0, c11 = fh1 * fw1;
    const unsigned char* q00 = S7 + ((size_t)(bc * 256 + h0 * 16 + w0)) * 256;
    const unsigned char* q01 = S7 + ((size_t)(bc * 256 + h0 * 16 + w1)) * 256;
    const unsigned char* q10 = S7 + ((size_t)(bc * 256 + h1 * 16 + w0)) * 256;
    const unsigned char* q11 = S7 + ((size_t)(bc * 256 + h1 * 16 + w1)) * 256;
    unsigned char* o = S8 + (size_t)r * 256;
    float g1 = 0, g2 = 0, rr = 0;
    for (int t = 0; t < 256; ++t)
      o[t] = (unsigned char)snstep_i(
          c00 * q00[t] + c01 * q01[t] + c10 * q10[t] + c11 * q11[t], g1, g2, rr);
  }
  __syncthreads();
  // I: out = spike(psp(conv1x1 32->1 (s8))) -- overwrites pre-zeroed d_out
  for (int r = tid; r < 4096; r += 256) {
    const int b = r >> 10, pix = r & 1023;
    float* o = out + (size_t)r * 256;
    float g1 = 0, g2 = 0, rr = 0;
    for (int t = 0; t < 256; ++t) {
      float acc = 0.f;
      for (int c = 0; c < 32; ++c)
        acc += wout[c] * (float)S8[((size_t)((b * 32 + c) * 1024 + pix)) * 256 + t];
      o[t] = snstep(acc, g1, g2, rr);
    }
  }
}

// ---------------------------------------------------------------------------
// Orchestration: 2 launches. l1_fused (fp32, 4-channel split, 4096 blocks)
// decides spike-existence exactly (bound + scan, r<=0 invariant) and writes
// the common-case zero output; rare_chain exits immediately unless L1
// spiked, else recomputes L2..L9 exactly.
// ws map (256 MiB): Vr f32 @0 (64M) | S1@64M S2@81M S3@86M S4@95M S5@98M
// S6@103M S7@120M S8@129M (rare-path u8 spike buffers) | dpix@168M dirty@169M.
// ---------------------------------------------------------------------------
extern "C" void kernel_launch(void* const* d_in, const int* in_sizes, int n_in,
                              void* d_out, int out_size, void* d_ws, size_t ws_size,
                              hipStream_t stream) {
  const float* x    = (const float*)d_in[0];
  const float* w1   = (const float*)d_in[1];
  const float* w2   = (const float*)d_in[2];
  const float* w3   = (const float*)d_in[3];
  const float* w4   = (const float*)d_in[4];
  const float* wout = (const float*)d_in[5];
  char* ws = (char*)d_ws;
  float*         Vr = (float*)(ws);
  unsigned char* S1 = (unsigned char*)(ws + ((size_t)64  << 20));
  unsigned char* S2 = (unsigned char*)(ws + ((size_t)81  << 20));
  unsigned char* S3 = (unsigned char*)(ws + ((size_t)86  << 20));
  unsigned char* S4 = (unsigned char*)(ws + ((size_t)95  << 20));
  unsigned char* S5 = (unsigned char*)(ws + ((size_t)98  << 20));
  unsigned char* S6 = (unsigned char*)(ws + ((size_t)103 << 20));
  unsigned char* S7 = (unsigned char*)(ws + ((size_t)120 << 20));
  unsigned char* S8 = (unsigned char*)(ws + ((size_t)129 << 20));
  unsigned char* dpix = (unsigned char*)(ws + ((size_t)168 << 20));
  unsigned*      dirty = (unsigned*)(ws + ((size_t)169 << 20));
  float* out = (float*)d_out;

  // L1: conv5x5 + existence bound/scan + d_out zero; rare rows -> Vr
  l1_fused<<<4096, 256, 0, stream>>>(x, w1, Vr, dpix, dirty, out);
  // Gated exact recompute of the whole downstream (normally exits at once)
  rare_chain<<<1, 256, 0, stream>>>(Vr, dpix, dirty, w2, w3, w4, wout,
                                    S1, S2, S3, S4, S5, S6, S7, S8, out);
}

// Round 16
// 82.757 us; speedup vs baseline: 1.1234x; 1.0331x over previous
//
#include <hip/hip_runtime.h>

// SLAYER SRM-alpha constants (fp32-rounded from the reference doubles)
#define D_SR   0.90483741803595952f   // exp(-1/10)
#define D_REF  0.36787944117144233f   // exp(-1)
#define PSPSC  0.27182818284590454f   // e/10
#define THETA  10.0f
#define REFSC  20.0f                  // scaleRef * theta
#define POOLSC 2.75f                  // 1.1*theta/4
// Safe upper bound on the psp gain sum (e/10)*sum_{s} s*d^s = 27.160...
#define PSPBND 27.2f

// One SRM step: two cascaded IIR stages (alpha PSP), threshold, exp refractory.
__device__ __forceinline__ float snstep(float x, float& g1, float& g2, float& r) {
  g1 = D_SR * g1 + x;
  g2 = D_SR * g2 + g1;
  const float u = PSPSC * (g2 - g1) + r - THETA;
  const float s = (u >= 0.0f) ? 1.0f : 0.0f;
  r = D_REF * (r - REFSC * s);
  return s;
}

__device__ __forceinline__ int snstep_i(float x, float& g1, float& g2, float& r) {
  g1 = D_SR * g1 + x;
  g2 = D_SR * g2 + g1;
  const float u = PSPSC * (g2 - g1) + r - THETA;
  const int s = (u >= 0.0f) ? 1 : 0;
  r = D_REF * (r - REFSC * (float)s);
  return s;
}

// jax.image.resize bilinear 2x coeffs (clamped): validated absmax=0 R0-R15.
__device__ __forceinline__ void upcoef(int o, int I, int& i0, int& i1,
                                       float& f0, float& f1) {
  const int k = o >> 1;
  if (o & 1) { i0 = k; i1 = (k + 1 < I) ? k + 1 : I - 1; f0 = 0.75f; f1 = 0.25f; }
  else       { i0 = (k > 0) ? k - 1 : 0; i1 = k;         f0 = 0.25f; f1 = 0.75f; }
}

// ---------------------------------------------------------------------------
// L1 fused: conv5x5 (Ci=1) + psp + spike-existence + d_out zero.
// R16: REVERT to the measured-optimal R12 config — fp32 conv, 8 channels/
// block (cg = blockIdx&1, 2048 blocks). Tuning history: split 16->8 = +3.5us
// (R12), split 8->4 = -1.7us (R15, input re-read dominates), f16 pk_fma =
// -9us (R14). 8-ch/block is the sweet spot.
// Wave = one pixel's full T (lane = 4-step t-segment).
// Existence: r<=0 invariant => spike iff max_t a_t >= theta;
// |a_t| <= PSPBND*max|v| gives the cheap wave-uniform common-case exit.
// Rare: per-channel bound -> exact Kogge-Stone psp scan -> existence ->
// dump membrane to Vr + dpix/dirty for rare_chain.
// NOTE (R9 lesson): every loop touching acc[] MUST be fully unrolled —
// rolled loops dynamically index acc[] and demote it to scratch.
// Flags use ==1u semantics (0xAA ws-poison reads as unset -> no init).
// ---------------------------------------------------------------------------
#define SCANSTEP(DELTA, CK, MK)                                         \
  { float o1 = __shfl_up(s1v, DELTA, 64);                               \
    float o2 = __shfl_up(s2v, DELTA, 64);                               \
    if (lane < DELTA) { o1 = 0.f; o2 = 0.f; }                           \
    s2v = fmaf(CK, fmaf(MK, o1, o2), s2v);                              \
    s1v = fmaf(CK, o1, s1v); }

__global__ __launch_bounds__(256)
void l1_fused(const float* __restrict__ in, const float* __restrict__ wt,
              float* __restrict__ Vr, unsigned char* __restrict__ dpix,
              unsigned* __restrict__ dirty, float* __restrict__ dout) {
  const int H = 32, W = 32, K = 5, P = 2;
  __shared__ float wlds[25 * 8];
  const int tid = threadIdx.x;
  const int blk = blockIdx.x;
  const int b  = blk >> 9;                // 512 blocks / batch
  const int pg = (blk >> 1) & 255;        // 4-pixel group
  const int cg = blk & 1;                 // channel group: channels cg*8..+7
  for (int idx = tid; idx < 25 * 8; idx += 256) {
    const int co = idx & 7, kk = idx >> 3;
    wlds[idx] = wt[(cg * 8 + co) * 25 + kk];   // lds[kk*8+co]
  }
  __syncthreads();
  const int pl = tid >> 6, lane = tid & 63;
  const int pixel = pg * 4 + pl;
  const int h_ = pixel >> 5, w_ = pixel & 31;

  // d_out zero (common-case final answer; rare_chain overwrites if spikes)
  if (cg == 0) {
    *(float4*)(dout + (size_t)(b * 1024 + pixel) * 256 + lane * 4) =
        make_float4(0.f, 0.f, 0.f, 0.f);
  }

  float4 acc[8];
#pragma unroll
  for (int c = 0; c < 8; ++c) acc[c] = make_float4(0.f, 0.f, 0.f, 0.f);
  const float* inb = in + (size_t)b * H * W * 256;
#pragma unroll
  for (int kh = 0; kh < K; ++kh) {
    const int hh = h_ + kh - P;
    if (hh < 0 || hh >= H) continue;      // wave-uniform (lanes share pixel)
    float4 xr[5];
#pragma unroll
    for (int kw = 0; kw < K; ++kw) {
      const int ww = w_ + kw - P;
      xr[kw] = (ww >= 0 && ww < W)
                 ? *(const float4*)(inb + (size_t)(hh * W + ww) * 256 + lane * 4)
                 : make_float4(0.f, 0.f, 0.f, 0.f);
    }
#pragma unroll
    for (int kw = 0; kw < K; ++kw) {
      const float4 x = xr[kw];
      const float4* wr = (const float4*)&wlds[(kh * K + kw) * 8];
#pragma unroll
      for (int c4 = 0; c4 < 2; ++c4) {
        const float4 wv = wr[c4];
        acc[4*c4+0].x += x.x * wv.x; acc[4*c4+0].y += x.y * wv.x;
        acc[4*c4+0].z += x.z * wv.x; acc[4*c4+0].w += x.w * wv.x;
        acc[4*c4+1].x += x.x * wv.y; acc[4*c4+1].y += x.y * wv.y;
        acc[4*c4+1].z += x.z * wv.y; acc[4*c4+1].w += x.w * wv.y;
        acc[4*c4+2].x += x.x * wv.z; acc[4*c4+2].y += x.y * wv.z;
        acc[4*c4+2].z += x.z * wv.z; acc[4*c4+2].w += x.w * wv.z;
        acc[4*c4+3].x += x.x * wv.w; acc[4*c4+3].y += x.y * wv.w;
        acc[4*c4+3].z += x.z * wv.w; acc[4*c4+3].w += x.w * wv.w;
      }
    }
  }

  // Combined a-priori bound over this block's 8 channels: one wave reduce.
  float mxa = 0.f;
#pragma unroll
  for (int c = 0; c < 8; ++c) {
    mxa = fmaxf(mxa, fmaxf(fmaxf(fabsf(acc[c].x), fabsf(acc[c].y)),
                           fmaxf(fabsf(acc[c].z), fabsf(acc[c].w))));
  }
#pragma unroll
  for (int d = 1; d < 64; d <<= 1) mxa = fmaxf(mxa, __shfl_xor(mxa, d, 64));
  if (PSPBND * mxa < THETA) return;       // wave-uniform: no channel can spike

  // Rare: per-channel bound, then exact scan only where needed.
  // FULLY UNROLLED so acc[] stays in registers (R9 lesson).
#pragma unroll
  for (int c = 0; c < 8; ++c) {
    float mc = fmaxf(fmaxf(fabsf(acc[c].x), fabsf(acc[c].y)),
                     fmaxf(fabsf(acc[c].z), fabsf(acc[c].w)));
#pragma unroll
    for (int d = 1; d < 64; d <<= 1) mc = fmaxf(mc, __shfl_xor(mc, d, 64));
    if (PSPBND * mc >= THETA) {           // wave-uniform
      const float x0 = acc[c].x, x1 = acc[c].y, x2 = acc[c].z, x3 = acc[c].w;
      float g1 = x0, g2 = x0;             // local 4-step from zero state
      g1 = D_SR * g1 + x1; g2 = D_SR * g2 + g1;
      g1 = D_SR * g1 + x2; g2 = D_SR * g2 + g1;
      g1 = D_SR * g1 + x3; g2 = D_SR * g2 + g1;
      float s1v = g1, s2v = g2;           // inclusive KS scan (6 steps)
      SCANSTEP(1,  0.67032004603563930f,   4.f)
      SCANSTEP(2,  0.44932896411722156f,   8.f)
      SCANSTEP(4,  0.20189651799465538f,   16.f)
      SCANSTEP(8,  0.040762203978366215f,  32.f)
      SCANSTEP(16, 0.0016615572731739338f, 64.f)
      SCANSTEP(32, 2.7607725720371994e-06f, 128.f)
      float p1 = __shfl_up(s1v, 1, 64);   // exclusive seed
      float p2 = __shfl_up(s2v, 1, 64);
      if (lane == 0) { p1 = 0.f; p2 = 0.f; }
      float h1 = D_SR * p1 + x0, h2 = D_SR * p2 + h1;
      const float a0 = PSPSC * (h2 - h1);
      h1 = D_SR * h1 + x1; h2 = D_SR * h2 + h1;
      const float a1 = PSPSC * (h2 - h1);
      h1 = D_SR * h1 + x2; h2 = D_SR * h2 + h1;
      const float a2 = PSPSC * (h2 - h1);
      h1 = D_SR * h1 + x3; h2 = D_SR * h2 + h1;
      const float a3 = PSPSC * (h2 - h1);
      const float mx = fmaxf(fmaxf(a0, a1), fmaxf(a2, a3));
      if (__any((int)(mx >= THETA))) {    // exact: row has >=1 spike
        const int cglob = cg * 8 + c;
        *(float4*)(Vr + ((size_t)(b * 16 + cglob) * 1024 + pixel) * 256 + lane * 4)
            = make_float4(a0, a1, a2, a3);
        if (lane == 0) {
          dpix[(b * 16 + cglob) * 1024 + pixel] = 1;
          dirty[b * 16 + cglob] = 1u;
        }
      }
    }
  }
}
#undef SCANSTEP

// ---------------------------------------------------------------------------
// rare_chain: single-block exact recompute of L2..L9 when any L1 channel
// spiked. Common case: reads 64 dirty flags, exits in ~1 us. When active:
// straightforward fp32 reference-equivalent loops, __syncthreads between
// stages, all intermediates in ws. Slow but correct; never executes here.
// ---------------------------------------------------------------------------
__global__ __launch_bounds__(256)
void rare_chain(const float* __restrict__ Vr, const unsigned char* __restrict__ dpix,
                const unsigned* __restrict__ dirty,
                const float* __restrict__ w2, const float* __restrict__ w3,
                const float* __restrict__ w4, const float* __restrict__ wout,
                unsigned char* __restrict__ S1, unsigned char* __restrict__ S2,
                unsigned char* __restrict__ S3, unsigned char* __restrict__ S4,
                unsigned char* __restrict__ S5, unsigned char* __restrict__ S6,
                unsigned char* __restrict__ S7, unsigned char* __restrict__ S8,
                float* __restrict__ out) {
  unsigned any = 0;
  for (int i = 0; i < 64; ++i) any |= (dirty[i] == 1u) ? 1u : 0u;
  if (!any) return;                       // uniform fast exit (common)
  const int tid = threadIdx.x;

  // A: s1 spikes from dumped membranes (non-dumped rows provably spike-free)
  for (int r = tid; r < 65536; r += 256) {
    unsigned char* o = S1 + (size_t)r * 256;
    if (dpix[r] == 1) {
      const float* a = Vr + (size_t)r * 256;
      float rr = 0.f;
      for (int t = 0; t < 256; ++t) {
        const float u = a[t] + rr - THETA;
        const int s = (u >= 0.f) ? 1 : 0;
        rr = D_REF * (rr - REFSC * (float)s);
        o[t] = (unsigned char)s;
      }
    } else {
      for (int t = 0; t < 256; ++t) o[t] = 0;
    }
  }
  __syncthreads();
  // B: s2 = spike(psp(pool(s1))) [4,16,16,16]
  for (int r = tid; r < 16384; r += 256) {
    const int pw = r & 15, ph = (r >> 4) & 15, bc = r >> 8;
    const unsigned char* q0 = S1 + ((size_t)(bc * 1024 + (2 * ph) * 32 + 2 * pw)) * 256;
    const unsigned char* q1 = q0 + 256;
    const unsigned char* q2 = q0 + 32 * 256;
    const unsigned char* q3 = q2 + 256;
    unsigned char* o = S2 + (size_t)r * 256;
    float g1 = 0, g2 = 0, rr = 0;
    for (int t = 0; t < 256; ++t)
      o[t] = (unsigned char)snstep_i((float)(q0[t] + q1[t] + q2[t] + q3[t]) * POOLSC,
                                     g1, g2, rr);
  }
  __syncthreads();
  // C: s3 = spike(psp(conv3x3 16->32 (s2))) @16x16
  for (int r = tid; r < 32768; r += 256) {
    const int w_ = r & 15, h_ = (r >> 4) & 15;
    const int co = (r >> 8) & 31, b = r >> 13;
    unsigned char* o = S3 + (size_t)r * 256;
    float g1 = 0, g2 = 0, rr = 0;
    for (int t = 0; t < 256; ++t) {
      float acc = 0.f;
      for (int ci = 0; ci < 16; ++ci)
        for (int kh = 0; kh < 3; ++kh) {
          const int hh = h_ + kh - 1; if (hh < 0 || hh >= 16) continue;
          for (int kw = 0; kw < 3; ++kw) {
            const int ww = w_ + kw - 1; if (ww < 0 || ww >= 16) continue;
            acc += w2[((co * 16 + ci) * 3 + kh) * 3 + kw] *
                   (float)S2[((size_t)((b * 16 + ci) * 256 + hh * 16 + ww)) * 256 + t];
          }
        }
      o[t] = (unsigned char)snstep_i(acc, g1, g2, rr);
    }
  }
  __syncthreads();
  // D: s4 = spike(psp(pool(s3))) [4,32,8,8]
  for (int r = tid; r < 8192; r += 256) {
    const int pw = r & 7, ph = (r >> 3) & 7, bc = r >> 6;
    const unsigned char* q0 = S3 + ((size_t)(bc * 256 + (2 * ph) * 16 + 2 * pw)) * 256;
    const unsigned char* q1 = q0 + 256;
    const unsigned char* q2 = q0 + 16 * 256;
    const unsigned char* q3 = q2 + 256;
    unsigned char* o = S4 + (size_t)r * 256;
    float g1 = 0, g2 = 0, rr = 0;
    for (int t = 0; t < 256; ++t)
      o[t] = (unsigned char)snstep_i((float)(q0[t] + q1[t] + q2[t] + q3[t]) * POOLSC,
                                     g1, g2, rr);
  }
  __syncthreads();
  // E: s5 = spike(psp(conv3x3 32->64 (s4))) @8x8
  for (int r = tid; r < 16384; r += 256) {
    const int w_ = r & 7, h_ = (r >> 3) & 7;
    const int co = (r >> 6) & 63, b = r >> 12;
    unsigned char* o = S5 + (size_t)r * 256;
    float g1 = 0, g2 = 0, rr = 0;
    for (int t = 0; t < 256; ++t) {
      float acc = 0.f;
      for (int ci = 0; ci < 32; ++ci)
        for (int kh = 0; kh < 3; ++kh) {
          const int hh = h_ + kh - 1; if (hh < 0 || hh >= 8) continue;
          for (int kw = 0; kw < 3; ++kw) {
            const int ww = w_ + kw - 1; if (ww < 0 || ww >= 8) continue;
            acc += w3[((co * 32 + ci) * 3 + kh) * 3 + kw] *
                   (float)S4[((size_t)((b * 32 + ci) * 64 + hh * 8 + ww)) * 256 + t];
          }
        }
      o[t] = (unsigned char)snstep_i(acc, g1, g2, rr);
    }
  }
  __syncthreads();
  // F: s6 = spike(psp(up2(s5))) [4,64,16,16]
  for (int r = tid; r < 65536; r += 256) {
    const int ow = r & 15, oh = (r >> 4) & 15, bc = r >> 8;
    int h0, h1, w0, w1; float fh0, fh1, fw0, fw1;
    upcoef(oh, 8, h0, h1, fh0, fh1);
    upcoef(ow, 8, w0, w1, fw0, fw1);
    const float c00 = fh0 * fw0, c01 = fh0 * fw1, c10 = fh1 * fw0, c11 = fh1 * fw1;
    const unsigned char* q00 = S5 + ((size_t)(bc * 64 + h0 * 8 + w0)) * 256;
    const unsigned char* q01 = S5 + ((size_t)(bc * 64 + h0 * 8 + w1)) * 256;
    const unsigned char* q10 = S5 + ((size_t)(bc * 64 + h1 * 8 + w0)) * 256;
    const unsigned char* q11 = S5 + ((size_t)(bc * 64 + h1 * 8 + w1)) * 256;
    unsigned char* o = S6 + (size_t)r * 256;
    float g1 = 0, g2 = 0, rr = 0;
    for (int t = 0; t < 256; ++t)
      o[t] = (unsigned char)snstep_i(
          c00 * q00[t] + c01 * q01[t] + c10 * q10[t] + c11 * q11[t], g1, g2, rr);
  }
  __syncthreads();
  // G: s7 = spike(psp(conv3x3 64->32 (s6))) @16x16
  for (int r = tid; r < 32768; r += 256) {
    const int w_ = r & 15, h_ = (r >> 4) & 15;
    const int co = (r >> 8) & 31, b = r >> 13;
    unsigned char* o = S7 + (size_t)r * 256;
    float g1 = 0, g2 = 0, rr = 0;
    for (int t = 0; t < 256; ++t) {
      float acc = 0.f;
      for (int ci = 0; ci < 64; ++ci)
        for (int kh = 0; kh < 3; ++kh) {
          const int hh = h_ + kh - 1; if (hh < 0 || hh >= 16) continue;
          for (int kw = 0; kw < 3; ++kw) {
            const int ww = w_ + kw - 1; if (ww < 0 || ww >= 16) continue;
            acc += w4[((co * 64 + ci) * 3 + kh) * 3 + kw] *
                   (float)S6[((size_t)((b * 64 + ci) * 256 + hh * 16 + ww)) * 256 + t];
          }
        }
      o[t] = (unsigned char)snstep_i(acc, g1, g2, rr);
    }
  }
  __syncthreads();
  // H: s8 = spike(psp(up2(s7))) [4,32,32,32]
  for (int r = tid; r < 131072; r += 256) {
    const int ow = r & 31, oh = (r >> 5) & 31, bc = r >> 10;
    int h0, h1, w0, w1; float fh0, fh1, fw0, fw1;
    upcoef(oh, 16, h0, h1, fh0, fh1);
    upcoef(ow, 16, w0, w1, fw0, fw1);
    const float c00 = fh0 * fw0, c01 = fh0 * fw1, c10 = fh1 * fw0, c11 = fh1 * fw1;
    const unsigned char* q00 = S7 + ((size_t)(bc * 256 + h0 * 16 + w0)) * 256;
    const unsigned char* q01 = S7 + ((size_t)(bc * 256 + h0 * 16 + w1)) * 256;
    const unsigned char* q10 = S7 + ((size_t)(bc * 256 + h1 * 16 + w0)) * 256;
    const unsigned char* q11 = S7 + ((size_t)(bc * 256 + h1 * 16 + w1)) * 256;
    unsigned char* o = S8 + (size_t)r * 256;
    float g1 = 0, g2 = 0, rr = 0;
    for (int t = 0; t < 256; ++t)
      o[t] = (unsigned char)snstep_i(
          c00 * q00[t] + c01 * q01[t] + c10 * q10[t] + c11 * q11[t], g1, g2, rr);
  }
  __syncthreads();
  // I: out = spike(psp(conv1x1 32->1 (s8))) -- overwrites pre-zeroed d_out
  for (int r = tid; r < 4096; r += 256) {
    const int b = r >> 10, pix = r & 1023;
    float* o = out + (size_t)r * 256;
    float g1 = 0, g2 = 0, rr = 0;
    for (int t = 0; t < 256; ++t) {
      float acc = 0.f;
      for (int c = 0; c < 32; ++c)
        acc += wout[c] * (float)S8[((size_t)((b * 32 + c) * 1024 + pix)) * 256 + t];
      o[t] = snstep(acc, g1, g2, rr);
    }
  }
}

// ---------------------------------------------------------------------------
// Orchestration: 2 launches. l1_fused (fp32, 8-channel split, 2048 blocks —
// measured optimum) decides spike-existence exactly (bound + scan, r<=0
// invariant) and writes the common-case zero output; rare_chain exits
// immediately unless L1 spiked, else recomputes L2..L9 exactly.
// ws map (256 MiB): Vr f32 @0 (64M) | S1@64M S2@81M S3@86M S4@95M S5@98M
// S6@103M S7@120M S8@129M (rare-path u8 spike buffers) | dpix@168M dirty@169M.
// ---------------------------------------------------------------------------
extern "C" void kernel_launch(void* const* d_in, const int* in_sizes, int n_in,
                              void* d_out, int out_size, void* d_ws, size_t ws_size,
                              hipStream_t stream) {
  const float* x    = (const float*)d_in[0];
  const float* w1   = (const float*)d_in[1];
  const float* w2   = (const float*)d_in[2];
  const float* w3   = (const float*)d_in[3];
  const float* w4   = (const float*)d_in[4];
  const float* wout = (const float*)d_in[5];
  char* ws = (char*)d_ws;
  float*         Vr = (float*)(ws);
  unsigned char* S1 = (unsigned char*)(ws + ((size_t)64  << 20));
  unsigned char* S2 = (unsigned char*)(ws + ((size_t)81  << 20));
  unsigned char* S3 = (unsigned char*)(ws + ((size_t)86  << 20));
  unsigned char* S4 = (unsigned char*)(ws + ((size_t)95  << 20));
  unsigned char* S5 = (unsigned char*)(ws + ((size_t)98  << 20));
  unsigned char* S6 = (unsigned char*)(ws + ((size_t)103 << 20));
  unsigned char* S7 = (unsigned char*)(ws + ((size_t)120 << 20));
  unsigned char* S8 = (unsigned char*)(ws + ((size_t)129 << 20));
  unsigned char* dpix = (unsigned char*)(ws + ((size_t)168 << 20));
  unsigned*      dirty = (unsigned*)(ws + ((size_t)169 << 20));
  float* out = (float*)d_out;

  // L1: conv5x5 + existence bound/scan + d_out zero; rare rows -> Vr
  l1_fused<<<2048, 256, 0, stream>>>(x, w1, Vr, dpix, dirty, out);
  // Gated exact recompute of the whole downstream (normally exits at once)
  rare_chain<<<1, 256, 0, stream>>>(Vr, dpix, dirty, w2, w3, w4, wout,
                                    S1, S2, S3, S4, S5, S6, S7, S8, out);
}